// Round 14
// baseline (157.744 us; speedup 1.0000x reference)
//
#include <hip/hip_runtime.h>

#define BB 4
#define NN 2048
#define FF 128
#define NP 2176  // padded WhT row stride (shorts)
#define ALPHA 0.2f
#define SHIFT_C 16.0f  // exp(x-16): x=LR(f1+f2) bounded ~|10|; masked -> p=0 via bit-multiply

typedef short bf16x8 __attribute__((ext_vector_type(8)));
typedef float f32x4 __attribute__((ext_vector_type(4)));
typedef unsigned u32;

__device__ inline short f2bf(float f) {  // RNE float -> bf16 bits
    union { float f; unsigned u; } v; v.f = f;
    unsigned r = (v.u + 0x7FFFu + ((v.u >> 16) & 1u)) >> 16;
    return (short)r;
}
__device__ inline float bf2f(short s) {
    union { float f; unsigned u; } v;
    v.u = ((unsigned)(unsigned short)s) << 16;
    return v.f;
}

// ---------------------------------------------------------------------------
// k_wh v2 (passed R11/R12).
// ---------------------------------------------------------------------------
__global__ __launch_bounds__(256) void k_wh(const float* __restrict__ h,
                                            const float* __restrict__ W,
                                            const float* __restrict__ a,
                                            const int* __restrict__ adj,
                                            short* __restrict__ WhHiT,
                                            short* __restrict__ WhLoT,
                                            float* __restrict__ f1,
                                            float* __restrict__ f2,
                                            u32* __restrict__ adjp) {
    __shared__ float Wa[2 * FF];
    __shared__ float hs[16 * 132];  // 8.25 KB
    int tid = threadIdx.x;
    int r0 = blockIdx.x * 16;

    {
        int fin = tid & 127;
        const float* av = (tid < 128) ? a : (a + FF);
        const float* wr = W + (size_t)fin * FF;
        float s = 0.f;
        for (int o = 0; o < FF; o += 4) {
            float4 wv = *(const float4*)(wr + o);
            float4 avv = *(const float4*)(av + o);
            s += wv.x * avv.x + wv.y * avv.y + wv.z * avv.z + wv.w * avv.w;
        }
        Wa[(tid < 128 ? 0 : FF) + fin] = s;
    }
    {
        const float4* src = (const float4*)(h + (size_t)r0 * FF);
        float4* dst = (float4*)hs;
        dst[tid] = src[tid];
        dst[256 + tid] = src[256 + tid];
    }
    {
        int g = blockIdx.x * 256 + tid;
        int row = g >> 6, wd = g & 63;
        const int4* ar = (const int4*)(adj + (size_t)row * NN + wd * 32);
        u32 word = 0;
#pragma unroll
        for (int q = 0; q < 8; ++q) {
            int4 v = ar[q];
            word |= (u32)(v.x > 0) << (q * 4);
            word |= (u32)(v.y > 0) << (q * 4 + 1);
            word |= (u32)(v.z > 0) << (q * 4 + 2);
            word |= (u32)(v.w > 0) << (q * 4 + 3);
        }
        adjp[row * 64 + wd] = word;
    }
    __syncthreads();

    {
        int w = tid >> 6, lane = tid & 63;
        float wa1_0 = Wa[lane], wa1_1 = Wa[lane + 64];
        float wa2_0 = Wa[FF + lane], wa2_1 = Wa[FF + lane + 64];
        for (int rr = 0; rr < 4; ++rr) {
            int rloc = w * 4 + rr;
            int row = r0 + rloc;
            float x0 = hs[rloc * FF + lane], x1 = hs[rloc * FF + lane + 64];
            float s1 = x0 * wa1_0 + x1 * wa1_1;
            float s2 = x0 * wa2_0 + x1 * wa2_1;
#pragma unroll
            for (int m = 32; m >= 1; m >>= 1) {
                s1 += __shfl_xor(s1, m, 64);
                s2 += __shfl_xor(s2, m, 64);
            }
            if (lane == 0) { f1[row] = s1; f2[row] = s2; }
        }
    }

    int f4 = (tid & 31) * 4;
    int rg = tid >> 5;  // 0..7
    float acc[2][4];
#pragma unroll
    for (int rr = 0; rr < 2; ++rr)
#pragma unroll
        for (int cc = 0; cc < 4; ++cc) acc[rr][cc] = 0.f;

    for (int k0 = 0; k0 < FF; k0 += 4) {
        float4 wv[4];
#pragma unroll
        for (int kk = 0; kk < 4; ++kk)
            wv[kk] = *(const float4*)(W + (size_t)(k0 + kk) * FF + f4);
        float4 hv[2];
#pragma unroll
        for (int rr = 0; rr < 2; ++rr)
            hv[rr] = *(const float4*)(hs + (rg * 2 + rr) * FF + k0);
#pragma unroll
        for (int rr = 0; rr < 2; ++rr) {
            float hk[4] = {hv[rr].x, hv[rr].y, hv[rr].z, hv[rr].w};
#pragma unroll
            for (int kk = 0; kk < 4; ++kk) {
                acc[rr][0] += hk[kk] * wv[kk].x;
                acc[rr][1] += hk[kk] * wv[kk].y;
                acc[rr][2] += hk[kk] * wv[kk].z;
                acc[rr][3] += hk[kk] * wv[kk].w;
            }
        }
    }

    // LDS transpose + coalesced 16B stores
    __syncthreads();
    {
#pragma unroll
        for (int rr = 0; rr < 2; ++rr)
            *(float4*)(hs + (rg * 2 + rr) * 132 + f4) =
                make_float4(acc[rr][0], acc[rr][1], acc[rr][2], acc[rr][3]);
    }
    __syncthreads();
    {
        int fo = tid >> 1, jh = tid & 1;
        bf16x8 hv_, lv_;
#pragma unroll
        for (int jj = 0; jj < 8; ++jj) {
            float v = hs[(jh * 8 + jj) * 132 + fo];
            short hh = f2bf(v);
            hv_[jj] = hh;
            lv_[jj] = f2bf(v - bf2f(hh));
        }
        int b = r0 >> 11;
        int j0 = (r0 & (NN - 1)) + jh * 8;
        size_t off = (size_t)(b * FF + fo) * NP + j0;
        *(bf16x8*)(WhHiT + off) = hv_;
        *(bf16x8*)(WhLoT + off) = lv_;
    }
}

// ---------------------------------------------------------------------------
// k_attn v16 "128-row x 16-fo re-tile" (resubmit; round-13 bench was an
// infra failure, theory untested): second step along the R12-validated
// lever (fewer B-loads, more VALU cover, same MFMA). Block = 128 rows x
// 16 fo (512 blocks = 4b x 16 tiles x 8 fo-eighths; same grid, 2/CU).
// Per wave per step: 2 B-loads (was 4) + 64 EV (was 32) + 16 MFMA (same).
// B L2 traffic 134->67 MB; ~1200cy VALU/step covers L2 latency fully.
// EV duplication x8 (aggregate ~15us, but fills current stall cycles).
// v8-proven ordering: loads -> all 8 A-builds -> all 16 MFMA. Live ~110
// VGPR < 128 under (512,4) (no waves_per_eu games -- v11/v12 lesson).
// Epilogue: v15 merge generalized (images [16 col][32 row-quad], same XOR
// family, row_ps[8][128], row_inv[128]).
// ---------------------------------------------------------------------------
#define EV(f2v, f1v, wv, bi) ({ float _t = (f1v) + (f2v); float _x = fmaxf(_t, ALPHA * _t); \
    __expf(_x - SHIFT_C) * (float)(((wv) >> (bi)) & 1u); })

#define BUILD_A(Adst, F1V, WV, SP) { \
    float pa, pb; \
    pa = EV(q0.x, F1V, WV, bb + 0); pb = EV(q0.y, F1V, WV, bb + 1); \
    SP += pa + pb; \
    asm("v_cvt_pk_bf16_f32 %0, %1, %2" : "=v"(Adst.u[0]) : "v"(pa), "v"(pb)); \
    pa = EV(q0.z, F1V, WV, bb + 2); pb = EV(q0.w, F1V, WV, bb + 3); \
    SP += pa + pb; \
    asm("v_cvt_pk_bf16_f32 %0, %1, %2" : "=v"(Adst.u[1]) : "v"(pa), "v"(pb)); \
    pa = EV(q1.x, F1V, WV, bb + 4); pb = EV(q1.y, F1V, WV, bb + 5); \
    SP += pa + pb; \
    asm("v_cvt_pk_bf16_f32 %0, %1, %2" : "=v"(Adst.u[2]) : "v"(pa), "v"(pb)); \
    pa = EV(q1.z, F1V, WV, bb + 6); pb = EV(q1.w, F1V, WV, bb + 7); \
    SP += pa + pb; \
    asm("v_cvt_pk_bf16_f32 %0, %1, %2" : "=v"(Adst.u[3]) : "v"(pa), "v"(pb)); }

__global__ __launch_bounds__(512, 4) void k_attn(const short* __restrict__ WhHiT,
                                                 const short* __restrict__ WhLoT,
                                                 const u32* __restrict__ adjp,
                                                 const float* __restrict__ f1,
                                                 const float* __restrict__ f2,
                                                 float* __restrict__ out) {
    __shared__ __align__(16) char lds[70144];  // 8 x 8KB images + row_ps[8][128] 4KB + row_inv[128] 512B
    float* row_ps = (float*)(lds + 65536);     // [8][128]
    float* row_inv = (float*)(lds + 69632);    // [128]

    int tid = threadIdx.x;
    int w = tid >> 6, lane = tid & 63;
    int blk = blockIdx.x;                      // 512 = 4 b x 16 tile(128 rows) x 8 oc(16 fo)
    int b = blk >> 7;
    int tile = (blk >> 3) & 15;
    int oc = blk & 7;
    int i0 = tile * 128;

    int r_c = lane & 15, kg = lane >> 4;

    const float* f2b = f2 + b * NN;
    float f1m[8];
#pragma unroll
    for (int mi = 0; mi < 8; ++mi)
        f1m[mi] = f1[b * NN + i0 + mi * 16 + r_c];
    const u32* ap0 = adjp + (size_t)(i0 + r_c) * 64;  // row (i0+r_c); mi offset = mi*16*64

    // B-fragment row pointer (hi); lo at constant element delta
    const ptrdiff_t dLo = (ptrdiff_t)BB * FF * NP;
    int s0 = w * 8;  // this wave's 8 contiguous j-steps
    const short* pB0 = WhHiT + (size_t)(b * FF + oc * 16 + r_c) * NP + s0 * 32 + kg * 8;

    f32x4 acc[8];
#pragma unroll
    for (int mi = 0; mi < 8; ++mi) acc[mi] = (f32x4){0, 0, 0, 0};
    float spv[8];
#pragma unroll
    for (int mi = 0; mi < 8; ++mi) spv[mi] = 0.f;

#pragma unroll
    for (int s8 = 0; s8 < 8; ++s8) {
        int s = s0 + s8;
        // scalars for this step
        float4 q0 = *(const float4*)(f2b + s * 32 + kg * 8);
        float4 q1 = *(const float4*)(f2b + s * 32 + kg * 8 + 4);
        u32 wv_[8];
#pragma unroll
        for (int mi = 0; mi < 8; ++mi) wv_[mi] = ap0[mi * 1024 + s];
        // B loads (2 x 16B; consumed after ~1200cy of e-compute)
        bf16x8 bh = *(const bf16x8*)(pB0);
        bf16x8 bl = *(const bf16x8*)(pB0 + dLo);

        // all 8 A-builds first (v8-proven ordering), then all 16 MFMA
        union { u32 u[4]; bf16x8 v; } A[8];
        int bb = kg * 8;
#pragma unroll
        for (int mi = 0; mi < 8; ++mi)
            BUILD_A(A[mi], f1m[mi], wv_[mi], spv[mi])

#pragma unroll
        for (int mi = 0; mi < 8; ++mi) {
            acc[mi] = __builtin_amdgcn_mfma_f32_16x16x32_bf16(A[mi].v, bh, acc[mi], 0, 0, 0);
            acc[mi] = __builtin_amdgcn_mfma_f32_16x16x32_bf16(A[mi].v, bl, acc[mi], 0, 0, 0);
        }

        pB0 += 32;
    }

    // ---- epilogue ----
    // row sums: lanes {r_c, +16, +32, +48} hold k-slices of row mi*16+r_c
#pragma unroll
    for (int mi = 0; mi < 8; ++mi) {
        spv[mi] += __shfl_xor(spv[mi], 16, 64);
        spv[mi] += __shfl_xor(spv[mi], 32, 64);
    }
    if (lane < 16) {
#pragma unroll
        for (int mi = 0; mi < 8; ++mi)
            row_ps[w * 128 + mi * 16 + lane] = spv[mi];
    }
    // write this wave's partial image: [16 cols][32 row-quads] f32x4, XOR-swizzled
    {
        char* img = lds + w * 8192;
#pragma unroll
        for (int mi = 0; mi < 8; ++mi) {
            int ch = (r_c * 32 + mi * 4 + kg) ^ (r_c & 7);
            *(f32x4*)(img + ch * 16) = acc[mi];
        }
    }
    __syncthreads();
    if (tid < 128) {
        float t = 0.f;
#pragma unroll
        for (int ww = 0; ww < 8; ++ww) t += row_ps[ww * 128 + tid];
        row_inv[tid] = 1.0f / t;
    }
    __syncthreads();

    // merge 8 images + normalize + store.
    // wave w: cols w*2 + (lane>>5) (0..15 within eighth), row-quads rq = lane&31
    {
        int colg = w * 2 + (lane >> 5);
        int rq = lane & 31;
        int ch = (colg * 32 + rq) ^ (colg & 7);
        f32x4 v = {0, 0, 0, 0};
#pragma unroll
        for (int im = 0; im < 8; ++im)
            v += *(const f32x4*)(lds + im * 8192 + ch * 16);
        f32x4 rinv = *(const f32x4*)((char*)row_inv + rq * 16);
        float* ob = out + ((size_t)b * NN + i0 + rq * 4) * FF + oc * 16 + colg;
#pragma unroll
        for (int q = 0; q < 4; ++q)
            ob[(size_t)q * FF] = v[q] * rinv[q];
    }
}

// ---------------------------------------------------------------------------
extern "C" void kernel_launch(void* const* d_in, const int* in_sizes, int n_in,
                              void* d_out, int out_size, void* d_ws, size_t ws_size,
                              hipStream_t stream) {
    const float* h   = (const float*)d_in[0];
    const int*   adj = (const int*)d_in[1];
    const float* W   = (const float*)d_in[2];
    const float* a   = (const float*)d_in[3];
    float* out = (float*)d_out;

    short* WhHiT = (short*)d_ws;                          // 2.13 MB
    short* WhLoT = WhHiT + (size_t)BB * FF * NP;          // 2.13 MB
    float* f1 = (float*)(WhLoT + (size_t)BB * FF * NP);   // 32 KB
    float* f2 = f1 + (size_t)BB * NN;                     // 32 KB
    u32* adjp = (u32*)(f2 + (size_t)BB * NN);             // 512 KB (total ~4.83 MB, proven)

    k_wh<<<(BB * NN) / 16, 256, 0, stream>>>(h, W, a, adj, WhHiT, WhLoT, f1, f2, adjp);
    k_attn<<<512, 512, 0, stream>>>(WhHiT, WhLoT, adjp, f1, f2, out);
}

// Round 15
// 139.965 us; speedup vs baseline: 1.1270x; 1.1270x over previous
//
#include <hip/hip_runtime.h>

#define BB 4
#define NN 2048
#define FF 128
#define NP 2176  // padded WhT row stride (shorts)
#define ALPHA 0.2f
#define SHIFT_C 16.0f  // exp(x-16): x=LR(f1+f2) bounded ~|10|; masked -> p=0 via bit-multiply

typedef short bf16x8 __attribute__((ext_vector_type(8)));
typedef float f32x4 __attribute__((ext_vector_type(4)));
typedef unsigned u32;

__device__ inline short f2bf(float f) {  // RNE float -> bf16 bits
    union { float f; unsigned u; } v; v.f = f;
    unsigned r = (v.u + 0x7FFFu + ((v.u >> 16) & 1u)) >> 16;
    return (short)r;
}
__device__ inline float bf2f(short s) {
    union { float f; unsigned u; } v;
    v.u = ((unsigned)(unsigned short)s) << 16;
    return v.f;
}

// ---------------------------------------------------------------------------
// k_wh v2 (passed R11/R12/R14).
// ---------------------------------------------------------------------------
__global__ __launch_bounds__(256) void k_wh(const float* __restrict__ h,
                                            const float* __restrict__ W,
                                            const float* __restrict__ a,
                                            const int* __restrict__ adj,
                                            short* __restrict__ WhHiT,
                                            short* __restrict__ WhLoT,
                                            float* __restrict__ f1,
                                            float* __restrict__ f2,
                                            u32* __restrict__ adjp) {
    __shared__ float Wa[2 * FF];
    __shared__ float hs[16 * 132];  // 8.25 KB
    int tid = threadIdx.x;
    int r0 = blockIdx.x * 16;

    {
        int fin = tid & 127;
        const float* av = (tid < 128) ? a : (a + FF);
        const float* wr = W + (size_t)fin * FF;
        float s = 0.f;
        for (int o = 0; o < FF; o += 4) {
            float4 wv = *(const float4*)(wr + o);
            float4 avv = *(const float4*)(av + o);
            s += wv.x * avv.x + wv.y * avv.y + wv.z * avv.z + wv.w * avv.w;
        }
        Wa[(tid < 128 ? 0 : FF) + fin] = s;
    }
    {
        const float4* src = (const float4*)(h + (size_t)r0 * FF);
        float4* dst = (float4*)hs;
        dst[tid] = src[tid];
        dst[256 + tid] = src[256 + tid];
    }
    {
        int g = blockIdx.x * 256 + tid;
        int row = g >> 6, wd = g & 63;
        const int4* ar = (const int4*)(adj + (size_t)row * NN + wd * 32);
        u32 word = 0;
#pragma unroll
        for (int q = 0; q < 8; ++q) {
            int4 v = ar[q];
            word |= (u32)(v.x > 0) << (q * 4);
            word |= (u32)(v.y > 0) << (q * 4 + 1);
            word |= (u32)(v.z > 0) << (q * 4 + 2);
            word |= (u32)(v.w > 0) << (q * 4 + 3);
        }
        adjp[row * 64 + wd] = word;
    }
    __syncthreads();

    {
        int w = tid >> 6, lane = tid & 63;
        float wa1_0 = Wa[lane], wa1_1 = Wa[lane + 64];
        float wa2_0 = Wa[FF + lane], wa2_1 = Wa[FF + lane + 64];
        for (int rr = 0; rr < 4; ++rr) {
            int rloc = w * 4 + rr;
            int row = r0 + rloc;
            float x0 = hs[rloc * FF + lane], x1 = hs[rloc * FF + lane + 64];
            float s1 = x0 * wa1_0 + x1 * wa1_1;
            float s2 = x0 * wa2_0 + x1 * wa2_1;
#pragma unroll
            for (int m = 32; m >= 1; m >>= 1) {
                s1 += __shfl_xor(s1, m, 64);
                s2 += __shfl_xor(s2, m, 64);
            }
            if (lane == 0) { f1[row] = s1; f2[row] = s2; }
        }
    }

    int f4 = (tid & 31) * 4;
    int rg = tid >> 5;  // 0..7
    float acc[2][4];
#pragma unroll
    for (int rr = 0; rr < 2; ++rr)
#pragma unroll
        for (int cc = 0; cc < 4; ++cc) acc[rr][cc] = 0.f;

    for (int k0 = 0; k0 < FF; k0 += 4) {
        float4 wv[4];
#pragma unroll
        for (int kk = 0; kk < 4; ++kk)
            wv[kk] = *(const float4*)(W + (size_t)(k0 + kk) * FF + f4);
        float4 hv[2];
#pragma unroll
        for (int rr = 0; rr < 2; ++rr)
            hv[rr] = *(const float4*)(hs + (rg * 2 + rr) * FF + k0);
#pragma unroll
        for (int rr = 0; rr < 2; ++rr) {
            float hk[4] = {hv[rr].x, hv[rr].y, hv[rr].z, hv[rr].w};
#pragma unroll
            for (int kk = 0; kk < 4; ++kk) {
                acc[rr][0] += hk[kk] * wv[kk].x;
                acc[rr][1] += hk[kk] * wv[kk].y;
                acc[rr][2] += hk[kk] * wv[kk].z;
                acc[rr][3] += hk[kk] * wv[kk].w;
            }
        }
    }

    // LDS transpose + coalesced 16B stores
    __syncthreads();
    {
#pragma unroll
        for (int rr = 0; rr < 2; ++rr)
            *(float4*)(hs + (rg * 2 + rr) * 132 + f4) =
                make_float4(acc[rr][0], acc[rr][1], acc[rr][2], acc[rr][3]);
    }
    __syncthreads();
    {
        int fo = tid >> 1, jh = tid & 1;
        bf16x8 hv_, lv_;
#pragma unroll
        for (int jj = 0; jj < 8; ++jj) {
            float v = hs[(jh * 8 + jj) * 132 + fo];
            short hh = f2bf(v);
            hv_[jj] = hh;
            lv_[jj] = f2bf(v - bf2f(hh));
        }
        int b = r0 >> 11;
        int j0 = (r0 & (NN - 1)) + jh * 8;
        size_t off = (size_t)(b * FF + fo) * NP + j0;
        *(bf16x8*)(WhHiT + off) = hv_;
        *(bf16x8*)(WhLoT + off) = lv_;
    }
}

// ---------------------------------------------------------------------------
// k_attn v17 "64-row x 16-fo, live-set <= 64, true 8 waves/SIMD": v16's
// spill located the failure (8 A-frags live at once under the allocator's
// hard 64-VGPR attractor -- it spills rather than allocate 65-128; seen in
// v9/v16, serialized in v10/v13). v17 is the one untested cell: a structure
// whose live set GENUINELY fits 64. Block = 64 rows x 16 fo -> 1024 blocks
// (4/CU) x 512 thr. Per wave per step: 2 B-loads + 4 x (build-A -> 2 MFMA)
// INTERLEAVED so only one A-frag is live (acc 16 + A 4 + B 8 + scalars ~30
// ~= 58 regs). 64-reg allocation -> 8 waves/SIMD at 4 blocks/CU = 32
// waves/CU full occupancy -- the v11/v12 goal without fighting the
// allocator. B traffic 134 MB (= v15); EV dup x8 (~17us aggregate VALU
// floor) at 2x issue width. LDS 34.3 KB (8 x 4KB images + sums).
// Plain __launch_bounds__(512): no min-waves, no waves_per_eu.
// ---------------------------------------------------------------------------
#define EV(f2v, f1v, wv, bi) ({ float _t = (f1v) + (f2v); float _x = fmaxf(_t, ALPHA * _t); \
    __expf(_x - SHIFT_C) * (float)(((wv) >> (bi)) & 1u); })

#define BUILD_A(Adst, F1V, WV, SP) { \
    float pa, pb; \
    pa = EV(q0.x, F1V, WV, bb + 0); pb = EV(q0.y, F1V, WV, bb + 1); \
    SP += pa + pb; \
    asm("v_cvt_pk_bf16_f32 %0, %1, %2" : "=v"(Adst.u[0]) : "v"(pa), "v"(pb)); \
    pa = EV(q0.z, F1V, WV, bb + 2); pb = EV(q0.w, F1V, WV, bb + 3); \
    SP += pa + pb; \
    asm("v_cvt_pk_bf16_f32 %0, %1, %2" : "=v"(Adst.u[1]) : "v"(pa), "v"(pb)); \
    pa = EV(q1.x, F1V, WV, bb + 4); pb = EV(q1.y, F1V, WV, bb + 5); \
    SP += pa + pb; \
    asm("v_cvt_pk_bf16_f32 %0, %1, %2" : "=v"(Adst.u[2]) : "v"(pa), "v"(pb)); \
    pa = EV(q1.z, F1V, WV, bb + 6); pb = EV(q1.w, F1V, WV, bb + 7); \
    SP += pa + pb; \
    asm("v_cvt_pk_bf16_f32 %0, %1, %2" : "=v"(Adst.u[3]) : "v"(pa), "v"(pb)); }

__global__ __launch_bounds__(512) void k_attn(const short* __restrict__ WhHiT,
                                              const short* __restrict__ WhLoT,
                                              const u32* __restrict__ adjp,
                                              const float* __restrict__ f1,
                                              const float* __restrict__ f2,
                                              float* __restrict__ out) {
    __shared__ __align__(16) char lds[35072];  // 8 x 4KB images + row_ps[8][64] 2KB + row_inv[64] 256B
    float* row_ps = (float*)(lds + 32768);     // [8][64]
    float* row_inv = (float*)(lds + 34816);    // [64]

    int tid = threadIdx.x;
    int w = tid >> 6, lane = tid & 63;
    int blk = blockIdx.x;                      // 1024 = 4 b x 32 tile(64 rows) x 8 oc(16 fo)
    int b = blk >> 8;
    int tile = (blk >> 3) & 31;
    int oc = blk & 7;
    int i0 = tile * 64;

    int r_c = lane & 15, kg = lane >> 4;

    const float* f2b = f2 + b * NN;
    float f1m[4];
#pragma unroll
    for (int mi = 0; mi < 4; ++mi)
        f1m[mi] = f1[b * NN + i0 + mi * 16 + r_c];
    const u32* ap0 = adjp + (size_t)(i0 + r_c) * 64;  // row (i0+r_c); mi offset = mi*16*64 = mi*1024

    // B-fragment row pointer (hi); lo at constant element delta
    const ptrdiff_t dLo = (ptrdiff_t)BB * FF * NP;
    int s0 = w * 8;  // this wave's 8 contiguous j-steps
    const short* pB0 = WhHiT + (size_t)(b * FF + oc * 16 + r_c) * NP + s0 * 32 + kg * 8;

    f32x4 acc0 = {0,0,0,0}, acc1 = {0,0,0,0}, acc2 = {0,0,0,0}, acc3 = {0,0,0,0};
    float sp0 = 0.f, sp1 = 0.f, sp2 = 0.f, sp3 = 0.f;

#pragma unroll
    for (int s8 = 0; s8 < 8; ++s8) {
        int s = s0 + s8;
        // scalars + B loads for this step
        float4 q0 = *(const float4*)(f2b + s * 32 + kg * 8);
        float4 q1 = *(const float4*)(f2b + s * 32 + kg * 8 + 4);
        u32 w0 = ap0[s], w1 = ap0[1024 + s], w2 = ap0[2048 + s], w3 = ap0[3072 + s];
        bf16x8 bh = *(const bf16x8*)(pB0);
        bf16x8 bl = *(const bf16x8*)(pB0 + dLo);

        int bb = kg * 8;
        // interleaved: one A-frag live at a time (live set fits 64 VGPR)
        {
            union { u32 u[4]; bf16x8 v; } A;
            BUILD_A(A, f1m[0], w0, sp0)
            acc0 = __builtin_amdgcn_mfma_f32_16x16x32_bf16(A.v, bh, acc0, 0, 0, 0);
            acc0 = __builtin_amdgcn_mfma_f32_16x16x32_bf16(A.v, bl, acc0, 0, 0, 0);
        }
        {
            union { u32 u[4]; bf16x8 v; } A;
            BUILD_A(A, f1m[1], w1, sp1)
            acc1 = __builtin_amdgcn_mfma_f32_16x16x32_bf16(A.v, bh, acc1, 0, 0, 0);
            acc1 = __builtin_amdgcn_mfma_f32_16x16x32_bf16(A.v, bl, acc1, 0, 0, 0);
        }
        {
            union { u32 u[4]; bf16x8 v; } A;
            BUILD_A(A, f1m[2], w2, sp2)
            acc2 = __builtin_amdgcn_mfma_f32_16x16x32_bf16(A.v, bh, acc2, 0, 0, 0);
            acc2 = __builtin_amdgcn_mfma_f32_16x16x32_bf16(A.v, bl, acc2, 0, 0, 0);
        }
        {
            union { u32 u[4]; bf16x8 v; } A;
            BUILD_A(A, f1m[3], w3, sp3)
            acc3 = __builtin_amdgcn_mfma_f32_16x16x32_bf16(A.v, bh, acc3, 0, 0, 0);
            acc3 = __builtin_amdgcn_mfma_f32_16x16x32_bf16(A.v, bl, acc3, 0, 0, 0);
        }

        pB0 += 32;
    }

    // ---- epilogue ----
    // row sums: lanes {r_c, +16, +32, +48} hold k-slices of row mi*16+r_c
    sp0 += __shfl_xor(sp0, 16, 64); sp0 += __shfl_xor(sp0, 32, 64);
    sp1 += __shfl_xor(sp1, 16, 64); sp1 += __shfl_xor(sp1, 32, 64);
    sp2 += __shfl_xor(sp2, 16, 64); sp2 += __shfl_xor(sp2, 32, 64);
    sp3 += __shfl_xor(sp3, 16, 64); sp3 += __shfl_xor(sp3, 32, 64);
    if (lane < 16) {
        row_ps[w * 64 + lane]      = sp0;
        row_ps[w * 64 + 16 + lane] = sp1;
        row_ps[w * 64 + 32 + lane] = sp2;
        row_ps[w * 64 + 48 + lane] = sp3;
    }
    // write this wave's partial image: [16 cols][16 row-quads] f32x4, XOR-swizzled
    {
        char* img = lds + w * 4096;
#define STACC(MI, A) { int ch = (r_c * 16 + (MI) * 4 + kg) ^ (r_c & 7); \
                       *(f32x4*)(img + ch * 16) = (A); }
        STACC(0, acc0) STACC(1, acc1) STACC(2, acc2) STACC(3, acc3)
#undef STACC
    }
    __syncthreads();
    if (tid < 64) {
        float t = 0.f;
#pragma unroll
        for (int ww = 0; ww < 8; ++ww) t += row_ps[ww * 64 + tid];
        row_inv[tid] = 1.0f / t;
    }
    __syncthreads();

    // merge 8 images + normalize + store.
    // wave w, lanes<32: cols w*2 + (lane>>4) (0..15), row-quads rq = lane&15
    if (lane < 32) {
        int colg = w * 2 + (lane >> 4);
        int rq = lane & 15;
        int ch = (colg * 16 + rq) ^ (colg & 7);
        f32x4 v = {0, 0, 0, 0};
#pragma unroll
        for (int im = 0; im < 8; ++im)
            v += *(const f32x4*)(lds + im * 4096 + ch * 16);
        f32x4 rinv = *(const f32x4*)((char*)row_inv + rq * 16);
        float* ob = out + ((size_t)b * NN + i0 + rq * 4) * FF + oc * 16 + colg;
#pragma unroll
        for (int q = 0; q < 4; ++q)
            ob[(size_t)q * FF] = v[q] * rinv[q];
    }
}

// ---------------------------------------------------------------------------
extern "C" void kernel_launch(void* const* d_in, const int* in_sizes, int n_in,
                              void* d_out, int out_size, void* d_ws, size_t ws_size,
                              hipStream_t stream) {
    const float* h   = (const float*)d_in[0];
    const int*   adj = (const int*)d_in[1];
    const float* W   = (const float*)d_in[2];
    const float* a   = (const float*)d_in[3];
    float* out = (float*)d_out;

    short* WhHiT = (short*)d_ws;                          // 2.13 MB
    short* WhLoT = WhHiT + (size_t)BB * FF * NP;          // 2.13 MB
    float* f1 = (float*)(WhLoT + (size_t)BB * FF * NP);   // 32 KB
    float* f2 = f1 + (size_t)BB * NN;                     // 32 KB
    u32* adjp = (u32*)(f2 + (size_t)BB * NN);             // 512 KB (total ~4.83 MB, proven)

    k_wh<<<(BB * NN) / 16, 256, 0, stream>>>(h, W, a, adj, WhHiT, WhLoT, f1, f2, adjp);
    k_attn<<<1024, 512, 0, stream>>>(WhHiT, WhLoT, adjp, f1, f2, out);
}

// Round 16
// 129.873 us; speedup vs baseline: 1.2146x; 1.0777x over previous
//
#include <hip/hip_runtime.h>

#define BB 4
#define NN 2048
#define FF 128
#define NP 2176  // padded WhT row stride (shorts)
#define ALPHA 0.2f
#define SHIFT_C 16.0f  // exp(x-16): x=LR(f1+f2) bounded ~|10|; masked -> p=0 via bit-multiply

typedef short bf16x8 __attribute__((ext_vector_type(8)));
typedef float f32x4 __attribute__((ext_vector_type(4)));
typedef unsigned u32;

__device__ inline short f2bf(float f) {  // RNE float -> bf16 bits
    union { float f; unsigned u; } v; v.f = f;
    unsigned r = (v.u + 0x7FFFu + ((v.u >> 16) & 1u)) >> 16;
    return (short)r;
}
__device__ inline float bf2f(short s) {
    union { float f; unsigned u; } v;
    v.u = ((unsigned)(unsigned short)s) << 16;
    return v.f;
}

// ---------------------------------------------------------------------------
// k_wh v2 (passed R11/R12/R14/R15).
// ---------------------------------------------------------------------------
__global__ __launch_bounds__(256) void k_wh(const float* __restrict__ h,
                                            const float* __restrict__ W,
                                            const float* __restrict__ a,
                                            const int* __restrict__ adj,
                                            short* __restrict__ WhHiT,
                                            short* __restrict__ WhLoT,
                                            float* __restrict__ f1,
                                            float* __restrict__ f2,
                                            u32* __restrict__ adjp) {
    __shared__ float Wa[2 * FF];
    __shared__ float hs[16 * 132];  // 8.25 KB
    int tid = threadIdx.x;
    int r0 = blockIdx.x * 16;

    {
        int fin = tid & 127;
        const float* av = (tid < 128) ? a : (a + FF);
        const float* wr = W + (size_t)fin * FF;
        float s = 0.f;
        for (int o = 0; o < FF; o += 4) {
            float4 wv = *(const float4*)(wr + o);
            float4 avv = *(const float4*)(av + o);
            s += wv.x * avv.x + wv.y * avv.y + wv.z * avv.z + wv.w * avv.w;
        }
        Wa[(tid < 128 ? 0 : FF) + fin] = s;
    }
    {
        const float4* src = (const float4*)(h + (size_t)r0 * FF);
        float4* dst = (float4*)hs;
        dst[tid] = src[tid];
        dst[256 + tid] = src[256 + tid];
    }
    {
        int g = blockIdx.x * 256 + tid;
        int row = g >> 6, wd = g & 63;
        const int4* ar = (const int4*)(adj + (size_t)row * NN + wd * 32);
        u32 word = 0;
#pragma unroll
        for (int q = 0; q < 8; ++q) {
            int4 v = ar[q];
            word |= (u32)(v.x > 0) << (q * 4);
            word |= (u32)(v.y > 0) << (q * 4 + 1);
            word |= (u32)(v.z > 0) << (q * 4 + 2);
            word |= (u32)(v.w > 0) << (q * 4 + 3);
        }
        adjp[row * 64 + wd] = word;
    }
    __syncthreads();

    {
        int w = tid >> 6, lane = tid & 63;
        float wa1_0 = Wa[lane], wa1_1 = Wa[lane + 64];
        float wa2_0 = Wa[FF + lane], wa2_1 = Wa[FF + lane + 64];
        for (int rr = 0; rr < 4; ++rr) {
            int rloc = w * 4 + rr;
            int row = r0 + rloc;
            float x0 = hs[rloc * FF + lane], x1 = hs[rloc * FF + lane + 64];
            float s1 = x0 * wa1_0 + x1 * wa1_1;
            float s2 = x0 * wa2_0 + x1 * wa2_1;
#pragma unroll
            for (int m = 32; m >= 1; m >>= 1) {
                s1 += __shfl_xor(s1, m, 64);
                s2 += __shfl_xor(s2, m, 64);
            }
            if (lane == 0) { f1[row] = s1; f2[row] = s2; }
        }
    }

    int f4 = (tid & 31) * 4;
    int rg = tid >> 5;  // 0..7
    float acc[2][4];
#pragma unroll
    for (int rr = 0; rr < 2; ++rr)
#pragma unroll
        for (int cc = 0; cc < 4; ++cc) acc[rr][cc] = 0.f;

    for (int k0 = 0; k0 < FF; k0 += 4) {
        float4 wv[4];
#pragma unroll
        for (int kk = 0; kk < 4; ++kk)
            wv[kk] = *(const float4*)(W + (size_t)(k0 + kk) * FF + f4);
        float4 hv[2];
#pragma unroll
        for (int rr = 0; rr < 2; ++rr)
            hv[rr] = *(const float4*)(hs + (rg * 2 + rr) * FF + k0);
#pragma unroll
        for (int rr = 0; rr < 2; ++rr) {
            float hk[4] = {hv[rr].x, hv[rr].y, hv[rr].z, hv[rr].w};
#pragma unroll
            for (int kk = 0; kk < 4; ++kk) {
                acc[rr][0] += hk[kk] * wv[kk].x;
                acc[rr][1] += hk[kk] * wv[kk].y;
                acc[rr][2] += hk[kk] * wv[kk].z;
                acc[rr][3] += hk[kk] * wv[kk].w;
            }
        }
    }

    // LDS transpose + coalesced 16B stores
    __syncthreads();
    {
#pragma unroll
        for (int rr = 0; rr < 2; ++rr)
            *(float4*)(hs + (rg * 2 + rr) * 132 + f4) =
                make_float4(acc[rr][0], acc[rr][1], acc[rr][2], acc[rr][3]);
    }
    __syncthreads();
    {
        int fo = tid >> 1, jh = tid & 1;
        bf16x8 hv_, lv_;
#pragma unroll
        for (int jj = 0; jj < 8; ++jj) {
            float v = hs[(jh * 8 + jj) * 132 + fo];
            short hh = f2bf(v);
            hv_[jj] = hh;
            lv_[jj] = f2bf(v - bf2f(hh));
        }
        int b = r0 >> 11;
        int j0 = (r0 & (NN - 1)) + jh * 8;
        size_t off = (size_t)(b * FF + fo) * NP + j0;
        *(bf16x8*)(WhHiT + off) = hv_;
        *(bf16x8*)(WhLoT + off) = lv_;
    }
}

// ---------------------------------------------------------------------------
// k_attn v18 "EV-x4 sweet spot at 4 blocks/CU": combines the two validated
// results. The fo-width tradeoff is measured: fo=64 latency-bound (42us),
// fo=32 best (37us), fo=16 VALU-bound (57us, VALUBusy 75%). v18 = fo=32's
// EV-x4 duplication (aggregate VALU ~21us, half of v17's) in v17's
// interleaved <=64-reg structure (VGPR=48 proven, no spill): block =
// 32 rows x 32 fo -> 1024 blocks (4b x 64 tiles x 4 qt) x 512 thr = 4
// blocks/CU = 32 waves/CU -- doubling v15's wave count to overlap its
// ~16us of residual latency stall above the VALU floor. Per wave per
// step: 4 B-loads + 2 x (build-A -> 4 MFMA) interleaved (one A live).
// Live ~52-56 VGPR. Epilogue: v12's proven 32x32 geometry, v17's direct
// 8-image merge; LDS 33.9 KB (fits 4/CU). Plain __launch_bounds__(512).
// ---------------------------------------------------------------------------
#define EV(f2v, f1v, wv, bi) ({ float _t = (f1v) + (f2v); float _x = fmaxf(_t, ALPHA * _t); \
    __expf(_x - SHIFT_C) * (float)(((wv) >> (bi)) & 1u); })

#define BUILD_A(Adst, F1V, WV, SP) { \
    float pa, pb; \
    pa = EV(q0.x, F1V, WV, bb + 0); pb = EV(q0.y, F1V, WV, bb + 1); \
    SP += pa + pb; \
    asm("v_cvt_pk_bf16_f32 %0, %1, %2" : "=v"(Adst.u[0]) : "v"(pa), "v"(pb)); \
    pa = EV(q0.z, F1V, WV, bb + 2); pb = EV(q0.w, F1V, WV, bb + 3); \
    SP += pa + pb; \
    asm("v_cvt_pk_bf16_f32 %0, %1, %2" : "=v"(Adst.u[1]) : "v"(pa), "v"(pb)); \
    pa = EV(q1.x, F1V, WV, bb + 4); pb = EV(q1.y, F1V, WV, bb + 5); \
    SP += pa + pb; \
    asm("v_cvt_pk_bf16_f32 %0, %1, %2" : "=v"(Adst.u[2]) : "v"(pa), "v"(pb)); \
    pa = EV(q1.z, F1V, WV, bb + 6); pb = EV(q1.w, F1V, WV, bb + 7); \
    SP += pa + pb; \
    asm("v_cvt_pk_bf16_f32 %0, %1, %2" : "=v"(Adst.u[3]) : "v"(pa), "v"(pb)); }

__global__ __launch_bounds__(512) void k_attn(const short* __restrict__ WhHiT,
                                              const short* __restrict__ WhLoT,
                                              const u32* __restrict__ adjp,
                                              const float* __restrict__ f1,
                                              const float* __restrict__ f2,
                                              float* __restrict__ out) {
    __shared__ __align__(16) char lds[33920];  // 8 x 4KB images + row_ps[8][32] 1KB + row_inv[32] 128B
    float* row_ps = (float*)(lds + 32768);     // [8][32]
    float* row_inv = (float*)(lds + 33792);    // [32]

    int tid = threadIdx.x;
    int w = tid >> 6, lane = tid & 63;
    int blk = blockIdx.x;                      // 1024 = 4 b x 64 tile(32 rows) x 4 qt(32 fo)
    int b = blk >> 8;
    int tile = (blk >> 2) & 63;
    int qt = blk & 3;
    int i0 = tile * 32;

    int r_c = lane & 15, kg = lane >> 4;

    const float* f2b = f2 + b * NN;
    float f10 = f1[b * NN + i0 + r_c];        // mi=0 rows
    float f11 = f1[b * NN + i0 + 16 + r_c];   // mi=1 rows
    const u32* ap0 = adjp + (size_t)(i0 + r_c) * 64;  // mi=1 words at +1024

    // B-fragment row pointers (hi); lo at constant element delta
    const ptrdiff_t dLo = (ptrdiff_t)BB * FF * NP;
    int s0 = w * 8;  // this wave's 8 contiguous j-steps
    const short* pB0 = WhHiT + (size_t)(b * FF + qt * 32 + 0 * 16 + r_c) * NP + s0 * 32 + kg * 8;
    const short* pB1 = WhHiT + (size_t)(b * FF + qt * 32 + 1 * 16 + r_c) * NP + s0 * 32 + kg * 8;

    f32x4 acc0_0 = {0,0,0,0}, acc0_1 = {0,0,0,0};   // acc{ni}_{mi}
    f32x4 acc1_0 = {0,0,0,0}, acc1_1 = {0,0,0,0};
    float sp0 = 0.f, sp1 = 0.f;

#pragma unroll
    for (int s8 = 0; s8 < 8; ++s8) {
        int s = s0 + s8;
        // scalars + B loads for this step
        float4 q0 = *(const float4*)(f2b + s * 32 + kg * 8);
        float4 q1 = *(const float4*)(f2b + s * 32 + kg * 8 + 4);
        u32 w0 = ap0[s], w1 = ap0[1024 + s];
        bf16x8 bh0 = *(const bf16x8*)(pB0); bf16x8 bl0 = *(const bf16x8*)(pB0 + dLo);
        bf16x8 bh1 = *(const bf16x8*)(pB1); bf16x8 bl1 = *(const bf16x8*)(pB1 + dLo);

        int bb = kg * 8;
        // interleaved: one A-frag live at a time (live set fits 64 VGPR)
        {
            union { u32 u[4]; bf16x8 v; } A;
            BUILD_A(A, f10, w0, sp0)
            acc0_0 = __builtin_amdgcn_mfma_f32_16x16x32_bf16(A.v, bh0, acc0_0, 0, 0, 0);
            acc0_0 = __builtin_amdgcn_mfma_f32_16x16x32_bf16(A.v, bl0, acc0_0, 0, 0, 0);
            acc1_0 = __builtin_amdgcn_mfma_f32_16x16x32_bf16(A.v, bh1, acc1_0, 0, 0, 0);
            acc1_0 = __builtin_amdgcn_mfma_f32_16x16x32_bf16(A.v, bl1, acc1_0, 0, 0, 0);
        }
        {
            union { u32 u[4]; bf16x8 v; } A;
            BUILD_A(A, f11, w1, sp1)
            acc0_1 = __builtin_amdgcn_mfma_f32_16x16x32_bf16(A.v, bh0, acc0_1, 0, 0, 0);
            acc0_1 = __builtin_amdgcn_mfma_f32_16x16x32_bf16(A.v, bl0, acc0_1, 0, 0, 0);
            acc1_1 = __builtin_amdgcn_mfma_f32_16x16x32_bf16(A.v, bh1, acc1_1, 0, 0, 0);
            acc1_1 = __builtin_amdgcn_mfma_f32_16x16x32_bf16(A.v, bl1, acc1_1, 0, 0, 0);
        }

        pB0 += 32; pB1 += 32;
    }

    // ---- epilogue ----
    // row sums: lanes {r_c, +16, +32, +48} hold k-slices of the same rows
    sp0 += __shfl_xor(sp0, 16, 64); sp0 += __shfl_xor(sp0, 32, 64);
    sp1 += __shfl_xor(sp1, 16, 64); sp1 += __shfl_xor(sp1, 32, 64);
    if (lane < 16) {
        row_ps[w * 32 + lane] = sp0;
        row_ps[w * 32 + 16 + lane] = sp1;
    }
    // write this wave's partial image: [32 cols][8 row-quads] f32x4, XOR-swizzled
    {
        char* img = lds + w * 4096;
#define STACC(NI, MI, A) { int ch = (((NI)*16 + r_c) * 8 + (MI)*4 + kg) ^ (r_c & 7); \
                           *(f32x4*)(img + ch * 16) = (A); }
        STACC(0, 0, acc0_0) STACC(0, 1, acc0_1)
        STACC(1, 0, acc1_0) STACC(1, 1, acc1_1)
#undef STACC
    }
    __syncthreads();
    if (tid < 32) {
        float t = 0.f;
#pragma unroll
        for (int ww = 0; ww < 8; ++ww) t += row_ps[ww * 32 + tid];
        row_inv[tid] = 1.0f / t;
    }
    __syncthreads();

    // merge 8 images + normalize + store.
    // wave w, lanes<32: cols w*4 + (lane>>3) (0..31 within quarter), row-quads rq = lane&7
    if (lane < 32) {
        int colg = w * 4 + (lane >> 3);
        int rq = lane & 7;
        int ch = (colg * 8 + rq) ^ (colg & 7);
        f32x4 v = {0, 0, 0, 0};
#pragma unroll
        for (int im = 0; im < 8; ++im)
            v += *(const f32x4*)(lds + im * 4096 + ch * 16);
        f32x4 rinv = *(const f32x4*)((char*)row_inv + rq * 16);
        float* ob = out + ((size_t)b * NN + i0 + rq * 4) * FF + qt * 32 + colg;
#pragma unroll
        for (int q = 0; q < 4; ++q)
            ob[(size_t)q * FF] = v[q] * rinv[q];
    }
}

// ---------------------------------------------------------------------------
extern "C" void kernel_launch(void* const* d_in, const int* in_sizes, int n_in,
                              void* d_out, int out_size, void* d_ws, size_t ws_size,
                              hipStream_t stream) {
    const float* h   = (const float*)d_in[0];
    const int*   adj = (const int*)d_in[1];
    const float* W   = (const float*)d_in[2];
    const float* a   = (const float*)d_in[3];
    float* out = (float*)d_out;

    short* WhHiT = (short*)d_ws;                          // 2.13 MB
    short* WhLoT = WhHiT + (size_t)BB * FF * NP;          // 2.13 MB
    float* f1 = (float*)(WhLoT + (size_t)BB * FF * NP);   // 32 KB
    float* f2 = f1 + (size_t)BB * NN;                     // 32 KB
    u32* adjp = (u32*)(f2 + (size_t)BB * NN);             // 512 KB (total ~4.83 MB, proven)

    k_wh<<<(BB * NN) / 16, 256, 0, stream>>>(h, W, a, adj, WhHiT, WhLoT, f1, f2, adjp);
    k_attn<<<1024, 512, 0, stream>>>(WhHiT, WhLoT, adjp, f1, f2, out);
}